// Round 5
// baseline (246.848 us; speedup 1.0000x reference)
//
#include <hip/hip_runtime.h>
#include <hip/hip_bf16.h>

typedef unsigned short u16;
typedef unsigned long long u64;
typedef __bf16 bf16x8 __attribute__((ext_vector_type(8)));
typedef float f32x4 __attribute__((ext_vector_type(4)));

#define DIM 1024
#define NH 16
#define HD 64
// 0.125 * log2(e): folds the 1/sqrt(64) score scale and the exp->exp2 change of base
#define QSCALE 0.180336880972788f

__device__ __forceinline__ u16 f2bf(float f) {
  union { float f; unsigned u; } v; v.f = f;
  unsigned r = v.u + 0x7fffu + ((v.u >> 16) & 1u);
  return (u16)(r >> 16);
}

__device__ __forceinline__ unsigned pk2(float a, float b) {
  union { __hip_bfloat162 h; unsigned u; } cv;
  cv.h = __float22bfloat162_rn(make_float2(a, b));
  return cv.u;
}

__device__ __forceinline__ float bf2f(unsigned s) {
  union { unsigned u; float f; } v; v.u = s << 16; return v.f;
}

__device__ __forceinline__ float fexp2(float x) {
#if __has_builtin(__builtin_amdgcn_exp2f)
  return __builtin_amdgcn_exp2f(x);   // raw v_exp_f32, no OCML denormal fixup
#else
  return exp2f(x);
#endif
}

__device__ __forceinline__ void gld16(const u16* gp, u16* lp) {
  __builtin_amdgcn_global_load_lds(
      (const __attribute__((address_space(1))) unsigned int*)(const void*)gp,
      (__attribute__((address_space(3))) unsigned int*)(void*)lp, 16, 0, 0);
}

// ---------------- Fused prep: 2x LayerNorm + 4x weight transpose ----------------
__global__ __launch_bounds__(256) void prep_kernel(
    const float* __restrict__ q, const float* __restrict__ c,
    const float* __restrict__ gq, const float* __restrict__ bq,
    const float* __restrict__ gkv, const float* __restrict__ bkv,
    u16* __restrict__ qn, u16* __restrict__ cn,
    const float* W0, const float* W1, const float* W2, const float* W3,
    u16* O0, u16* O1, u16* O2, u16* O3) {
  __shared__ float red[2][4];
  __shared__ float t[32][33];
  int bid = blockIdx.x, tid = threadIdx.x;
  if (bid < 8192) {
    const float* x  = bid < 4096 ? q : c;
    const float* g  = bid < 4096 ? gq : gkv;
    const float* be = bid < 4096 ? bq : bkv;
    u16* out = bid < 4096 ? qn : cn;
    int row = bid & 4095;
    float4 v = ((const float4*)(x + (size_t)row * DIM))[tid];
    float s1 = v.x + v.y + v.z + v.w;
    float s2 = v.x * v.x + v.y * v.y + v.z * v.z + v.w * v.w;
#pragma unroll
    for (int o = 32; o >= 1; o >>= 1) { s1 += __shfl_xor(s1, o, 64); s2 += __shfl_xor(s2, o, 64); }
    int wv = tid >> 6;
    if ((tid & 63) == 0) { red[0][wv] = s1; red[1][wv] = s2; }
    __syncthreads();
    s1 = red[0][0] + red[0][1] + red[0][2] + red[0][3];
    s2 = red[1][0] + red[1][1] + red[1][2] + red[1][3];
    float mu = s1 * (1.f / DIM);
    float var = s2 * (1.f / DIM) - mu * mu;
    float rs = rsqrtf(var + 1e-5f);
    float4 gv = ((const float4*)g)[tid];
    float4 bv = ((const float4*)be)[tid];
    uint2 o2;
    o2.x = pk2((v.x - mu) * rs * gv.x + bv.x, (v.y - mu) * rs * gv.y + bv.y);
    o2.y = pk2((v.z - mu) * rs * gv.z + bv.z, (v.w - mu) * rs * gv.w + bv.w);
    ((uint2*)(out + (size_t)row * DIM))[tid] = o2;
  } else {
    int wid = bid - 8192;
    int z = wid >> 10;
    const float* W = z == 0 ? W0 : z == 1 ? W1 : z == 2 ? W2 : W3;
    u16* O        = z == 0 ? O0 : z == 1 ? O1 : z == 2 ? O2 : O3;
    int xy = wid & 1023;
    int bx = (xy & 31) * 32, by = (xy >> 5) * 32;
    int tx = tid & 31, ty = tid >> 5;
#pragma unroll
    for (int i = 0; i < 4; ++i) t[ty + i * 8][tx] = W[(size_t)(by + ty + i * 8) * DIM + bx + tx];
    __syncthreads();
#pragma unroll
    for (int i = 0; i < 4; ++i) O[(size_t)(bx + ty + i * 8) * DIM + by + tx] = f2bf(t[tx][ty + i * 8]);
  }
}

// ---------------- 128x128 bf16 MFMA GEMM (QKV fused) ----------------
// mode 0: bf16 row-major (K proj) | 1: bf16 *QSCALE (Q proj)
// mode 2: bf16 transposed per batch: out[(b*1024+n)*2048 + t] (V proj -> Vt)
//         computed with SWAPPED MFMA operands so C^T lands in C-layout and the
//         Vt store is contiguous along tokens (16 lanes x 2B = 32B segments).
struct GArg { const u16* A; const u16* Bt; const float* bias; void* out; int mode; };
struct GArg3 { GArg g[3]; };

__global__ __launch_bounds__(256) void gemm128(GArg3 args) {
  GArg ga = args.g[blockIdx.z];
  const u16* __restrict__ A  = ga.A;
  const u16* __restrict__ Bt = ga.Bt;
  __shared__ __align__(16) u16 sm[128 * 64 * 2];
  u16* As = sm;
  u16* Bs = sm + 128 * 64;
  int tid = threadIdx.x, wave = tid >> 6, lane = tid & 63;
  int lr = lane & 15, quad = lane >> 4;
  int m0 = blockIdx.x * 128, n0 = blockIdx.y * 128;
  int wm = (wave >> 1) * 64, wn = (wave & 1) * 64;
  int mode = ga.mode;
  f32x4 acc[4][4] = {};
  for (int kt = 0; kt < DIM; kt += 64) {
#pragma unroll
    for (int r = 0; r < 4; ++r) {
      int slot = tid + r * 256;
      int row = slot >> 3;
      int c = (slot & 7) ^ (row & 7);
      gld16(A + (size_t)(m0 + row) * DIM + kt + c * 8, &As[slot * 8]);
    }
#pragma unroll
    for (int r = 0; r < 4; ++r) {
      int slot = tid + r * 256;
      int row = slot >> 3;
      int c = (slot & 7) ^ (row & 7);
      gld16(Bt + (size_t)(n0 + row) * DIM + kt + c * 8, &Bs[slot * 8]);
    }
    __syncthreads();
#pragma unroll
    for (int kc = 0; kc < 2; ++kc) {
      int pc = ((kc * 4 + quad) ^ (lr & 7)) * 8;
      bf16x8 af[4], bfr[4];
#pragma unroll
      for (int i = 0; i < 4; ++i) {
        af[i]  = *(const bf16x8*)&As[(wm + i * 16 + lr) * 64 + pc];
        bfr[i] = *(const bf16x8*)&Bs[(wn + i * 16 + lr) * 64 + pc];
      }
      if (mode != 2) {
#pragma unroll
        for (int mi = 0; mi < 4; ++mi)
#pragma unroll
          for (int ni = 0; ni < 4; ++ni)
            acc[mi][ni] = __builtin_amdgcn_mfma_f32_16x16x32_bf16(af[mi], bfr[ni], acc[mi][ni], 0, 0, 0);
      } else {
#pragma unroll
        for (int mi = 0; mi < 4; ++mi)
#pragma unroll
          for (int ni = 0; ni < 4; ++ni)
            acc[mi][ni] = __builtin_amdgcn_mfma_f32_16x16x32_bf16(bfr[ni], af[mi], acc[mi][ni], 0, 0, 0);
      }
    }
    __syncthreads();
  }
  const float* bias = ga.bias;
  if (mode == 2) {
    // acc[mi][ni] = C^T tile: col(lane&15) = token m, row(quad*4+r) = out-channel n
#pragma unroll
    for (int mi = 0; mi < 4; ++mi) {
      int m = m0 + wm + mi * 16 + lr;
      int bb = m >> 11, tt = m & 2047;
      u16* outb = (u16*)ga.out + (((size_t)bb << 10)) * 2048 + tt;
#pragma unroll
      for (int ni = 0; ni < 4; ++ni) {
        int nbase = n0 + wn + ni * 16 + quad * 4;
#pragma unroll
        for (int r = 0; r < 4; ++r)
          outb[(size_t)(nbase + r) * 2048] = f2bf(acc[mi][ni][r] + bias[nbase + r]);
      }
    }
  } else {
    float sc = (mode == 1) ? QSCALE : 1.f;
#pragma unroll
    for (int mi = 0; mi < 4; ++mi)
#pragma unroll
      for (int ni = 0; ni < 4; ++ni) {
        int col = n0 + wn + ni * 16 + lr;
        float bv = bias[col];
        int row0 = m0 + wm + mi * 16 + quad * 4;
#pragma unroll
        for (int r = 0; r < 4; ++r)
          ((u16*)ga.out)[(size_t)(row0 + r) * DIM + col] = f2bf((acc[mi][ni][r] + bv) * sc);
      }
  }
}

// ---------------- 128x64 GEMM, fp32 out + bias + residual (O proj) ----------------
__global__ __launch_bounds__(256) void gemm_o(const u16* __restrict__ A,
    const u16* __restrict__ Bt, const float* __restrict__ bias,
    float* __restrict__ out, const float* __restrict__ resid) {
  __shared__ __align__(16) u16 sm[(128 + 64) * 64];
  u16* As = sm;
  u16* Bs = sm + 128 * 64;
  int tid = threadIdx.x, wave = tid >> 6, lane = tid & 63;
  int lr = lane & 15, quad = lane >> 4;
  int m0 = blockIdx.x * 128, n0 = blockIdx.y * 64;
  int wm = (wave >> 1) * 64, wn = (wave & 1) * 32;
  f32x4 acc[4][2] = {};
  for (int kt = 0; kt < DIM; kt += 64) {
#pragma unroll
    for (int r = 0; r < 4; ++r) {
      int slot = tid + r * 256;
      int row = slot >> 3;
      int c = (slot & 7) ^ (row & 7);
      gld16(A + (size_t)(m0 + row) * DIM + kt + c * 8, &As[slot * 8]);
    }
#pragma unroll
    for (int r = 0; r < 2; ++r) {
      int slot = tid + r * 256;
      int row = slot >> 3;
      int c = (slot & 7) ^ (row & 7);
      gld16(Bt + (size_t)(n0 + row) * DIM + kt + c * 8, &Bs[slot * 8]);
    }
    __syncthreads();
#pragma unroll
    for (int kc = 0; kc < 2; ++kc) {
      int pc = ((kc * 4 + quad) ^ (lr & 7)) * 8;
      bf16x8 af[4], bfr[2];
#pragma unroll
      for (int i = 0; i < 4; ++i) af[i] = *(const bf16x8*)&As[(wm + i * 16 + lr) * 64 + pc];
#pragma unroll
      for (int j = 0; j < 2; ++j) bfr[j] = *(const bf16x8*)&Bs[(wn + j * 16 + lr) * 64 + pc];
#pragma unroll
      for (int mi = 0; mi < 4; ++mi)
#pragma unroll
        for (int ni = 0; ni < 2; ++ni)
          acc[mi][ni] = __builtin_amdgcn_mfma_f32_16x16x32_bf16(af[mi], bfr[ni], acc[mi][ni], 0, 0, 0);
    }
    __syncthreads();
  }
#pragma unroll
  for (int mi = 0; mi < 4; ++mi)
#pragma unroll
    for (int ni = 0; ni < 2; ++ni) {
      int col = n0 + wn + ni * 16 + lr;
      float bv = bias[col];
      int row0 = m0 + wm + mi * 16 + quad * 4;
#pragma unroll
      for (int r = 0; r < 4; ++r) {
        int row = row0 + r;
        out[(size_t)row * DIM + col] = acc[mi][ni][r] + bv + resid[(size_t)row * DIM + col];
      }
    }
}

// ---------------- Flash attention, split-K x2, 40KB LDS (4 blocks/CU) ----------
// Q,K: [B*2048,1024] bf16 (Q pre-scaled). Vt: [(b*1024+h*64+d)][token] bf16.
// LDS u16 layout: K0 @0, K1 @4096, V0 @8192, V1 @12288, P @16384 + wave*1024.
// P is 2KB/wave (32q x 32k), reused per kc-half; 16B-pair XOR swizzle.
__global__ __launch_bounds__(256) void flash_kernel(const u16* __restrict__ Q,
    const u16* __restrict__ Kg, const u16* __restrict__ Vt,
    u16* __restrict__ O0, u16* __restrict__ O1,
    float* __restrict__ L0, float* __restrict__ L1) {
  __shared__ __align__(16) u16 lds[20480];  // 40 KB
  int tid = threadIdx.x, wave = tid >> 6, lane = tid & 63;
  int lr = lane & 15, quad = lane >> 4;
  int bh = blockIdx.x, b = bh >> 4, h = bh & 15;
  int q0 = blockIdx.y * 128;
  int split = blockIdx.z;
  u16* Op = split ? O1 : O0;
  float* Lp = split ? L1 : L0;
  int t0 = split * 1024;

  const u16* kbase = Kg + (size_t)(b * 2048 + t0) * DIM + h * HD;
  const u16* vbase = Vt + (size_t)(b * 1024 + h * HD) * 2048 + t0;

  // Q fragments straight from global (one-time)
  bf16x8 qf[2][2];
#pragma unroll
  for (int s = 0; s < 2; ++s)
#pragma unroll
    for (int kc = 0; kc < 2; ++kc)
      qf[s][kc] = *(const bf16x8*)&Q[((size_t)(b * 2048 + q0 + wave * 32 + s * 16 + lr)) * DIM +
                                     h * HD + kc * 32 + quad * 8];

  // strength-reduced staging pointers
  int slot0 = tid, slot1 = tid + 256;
  int r0 = slot0 >> 3, c0 = (slot0 & 7) ^ (r0 & 7);
  int r1 = slot1 >> 3, c1 = (slot1 & 7) ^ (r1 & 7);
  const u16* kp0 = kbase + (size_t)r0 * DIM + c0 * 8;
  const u16* kp1 = kbase + (size_t)r1 * DIM + c1 * 8;
  const u16* vp0 = vbase + (size_t)r0 * 2048 + c0 * 8;
  const u16* vp1 = vbase + (size_t)r1 * 2048 + c1 * 8;

  gld16(kp0, &lds[slot0 * 8]);
  gld16(kp1, &lds[slot1 * 8]);
  gld16(vp0, &lds[8192 + slot0 * 8]);
  gld16(vp1, &lds[8192 + slot1 * 8]);
  __syncthreads();

  u16* Pw = &lds[16384 + wave * 1024];
  float plsum[2] = {0.f, 0.f};
  f32x4 oacc[2][4] = {};

  for (int j = 0; j < 16; ++j) {
    int par = j & 1;
    const u16* kcb = &lds[par * 4096];
    const u16* vcb = &lds[8192 + par * 4096];
    if (j < 15) {
      int np = par ^ 1;
      kp0 += 64 * DIM; kp1 += 64 * DIM; vp0 += 64; vp1 += 64;
      gld16(kp0, &lds[np * 4096 + slot0 * 8]);
      gld16(kp1, &lds[np * 4096 + slot1 * 8]);
      gld16(vp0, &lds[8192 + np * 4096 + slot0 * 8]);
      gld16(vp1, &lds[8192 + np * 4096 + slot1 * 8]);
    }

    // S^T = K . Q^T
    f32x4 sf[2][4] = {};
#pragma unroll
    for (int kc = 0; kc < 2; ++kc) {
      int pc = ((kc * 4 + quad) ^ (lr & 7)) * 8;
#pragma unroll
      for (int ns = 0; ns < 4; ++ns) {
        bf16x8 kf = *(const bf16x8*)&kcb[(ns * 16 + lr) * 64 + pc];
#pragma unroll
        for (int s = 0; s < 2; ++s)
          sf[s][ns] = __builtin_amdgcn_mfma_f32_16x16x32_bf16(kf, qf[s][kc], sf[s][ns], 0, 0, 0);
      }
    }

    // two kc-halves: exp -> P(2KB) -> PV
#pragma unroll
    for (int kc = 0; kc < 2; ++kc) {
#pragma unroll
      for (int s = 0; s < 2; ++s)
#pragma unroll
        for (int nsl = 0; nsl < 2; ++nsl) {
          int ns = kc * 2 + nsl;
          float p0 = fexp2(sf[s][ns][0]), p1 = fexp2(sf[s][ns][1]);
          float p2 = fexp2(sf[s][ns][2]), p3 = fexp2(sf[s][ns][3]);
          plsum[s] += (p0 + p1) + (p2 + p3);
          uint2 pk;
          pk.x = pk2(p0, p1);
          pk.y = pk2(p2, p3);
          int pp = (((nsl * 2 + (quad >> 1)) ^ (lr & 3)) * 8) + (quad & 1) * 4;
          *(uint2*)&Pw[(s * 16 + lr) * 32 + pp] = pk;
        }
      __threadfence_block();  // order wave-private P write -> read
      int pvc = ((kc * 4 + quad) ^ (lr & 7)) * 8;
      bf16x8 pf[2];
#pragma unroll
      for (int s = 0; s < 2; ++s)
        pf[s] = *(const bf16x8*)&Pw[(s * 16 + lr) * 32 + ((quad ^ (lr & 3)) * 8)];
#pragma unroll
      for (int ds = 0; ds < 4; ++ds) {
        bf16x8 vf = *(const bf16x8*)&vcb[(ds * 16 + lr) * 64 + pvc];
#pragma unroll
        for (int s = 0; s < 2; ++s)
          oacc[s][ds] = __builtin_amdgcn_mfma_f32_16x16x32_bf16(vf, pf[s], oacc[s][ds], 0, 0, 0);
      }
    }
    __syncthreads();
  }

#pragma unroll
  for (int s = 0; s < 2; ++s) {
    float l = plsum[s];
    l += __shfl_xor(l, 16, 64);
    l += __shfl_xor(l, 32, 64);
    size_t qrow = (size_t)(b * 2048 + q0 + wave * 32 + s * 16 + lr);
    if (quad == 0) Lp[qrow * 16 + h] = l;
#pragma unroll
    for (int ds = 0; ds < 4; ++ds) {
      uint2 pk;
      pk.x = pk2(oacc[s][ds][0], oacc[s][ds][1]);
      pk.y = pk2(oacc[s][ds][2], oacc[s][ds][3]);
      *(uint2*)&Op[qrow * DIM + h * HD + ds * 16 + quad * 4] = pk;
    }
  }
}

// ---------------- Combine split-K partials -> normalized bf16 AO ----------------
__global__ __launch_bounds__(256) void combine_kernel(const u16* __restrict__ O0,
    const u16* __restrict__ O1, const float* __restrict__ L0, const float* __restrict__ L1,
    u16* __restrict__ AO) {
  int row = blockIdx.x, tid = threadIdx.x;
  int h = tid >> 4;
  float rl = 1.f / (L0[row * 16 + h] + L1[row * 16 + h]);
  uint2 a = ((const uint2*)(O0 + (size_t)row * DIM))[tid];
  uint2 b = ((const uint2*)(O1 + (size_t)row * DIM))[tid];
  float v0 = (bf2f(a.x & 0xffff) + bf2f(b.x & 0xffff)) * rl;
  float v1 = (bf2f(a.x >> 16)    + bf2f(b.x >> 16))    * rl;
  float v2 = (bf2f(a.y & 0xffff) + bf2f(b.y & 0xffff)) * rl;
  float v3 = (bf2f(a.y >> 16)    + bf2f(b.y >> 16))    * rl;
  uint2 o;
  o.x = pk2(v0, v1);
  o.y = pk2(v2, v3);
  ((uint2*)(AO + (size_t)row * DIM))[tid] = o;
}

extern "C" void kernel_launch(void* const* d_in, const int* in_sizes, int n_in,
                              void* d_out, int out_size, void* d_ws, size_t ws_size,
                              hipStream_t stream) {
  const float* query   = (const float*)d_in[0];
  const float* context = (const float*)d_in[1];
  const float* Wq = (const float*)d_in[2];
  const float* bq = (const float*)d_in[3];
  const float* Wk = (const float*)d_in[4];
  const float* bk = (const float*)d_in[5];
  const float* Wv = (const float*)d_in[6];
  const float* bv = (const float*)d_in[7];
  const float* Wo = (const float*)d_in[8];
  const float* bo = (const float*)d_in[9];
  const float* gq    = (const float*)d_in[10];
  const float* betaq = (const float*)d_in[11];
  const float* gkv   = (const float*)d_in[12];
  const float* betakv= (const float*)d_in[13];
  (void)in_sizes; (void)n_in; (void)out_size; (void)ws_size;

  char* ws = (char*)d_ws;
  const size_t MB = (size_t)1 << 20;
  u16* qn  = (u16*)(ws + 0 * MB);   // dead after QKV gemm; reused by Op0
  u16* cn  = (u16*)(ws + 8 * MB);   // dead after QKV gemm; reused by Op1
  u16* Wqt = (u16*)(ws + 16 * MB);  // dead after QKV; L0/L1 alias here
  u16* Wkt = (u16*)(ws + 18 * MB);
  u16* Wvt = (u16*)(ws + 20 * MB);
  u16* Wot = (u16*)(ws + 22 * MB);  // alive until O proj
  u16* Qb  = (u16*)(ws + 24 * MB);
  u16* Kb  = (u16*)(ws + 32 * MB);
  u16* Vtb = (u16*)(ws + 40 * MB);
  u16* AOb = (u16*)(ws + 48 * MB);
  u16* Op0 = qn;
  u16* Op1 = cn;
  float* L0 = (float*)(ws + 16 * MB);
  float* L1 = (float*)(ws + 16 * MB + 256 * 1024);

  prep_kernel<<<12288, 256, 0, stream>>>(query, context, gq, betaq, gkv, betakv,
                                         qn, cn, Wq, Wk, Wv, Wo, Wqt, Wkt, Wvt, Wot);

  GArg3 a3;
  a3.g[0] = { qn, Wqt, bq, (void*)Qb,  1 };
  a3.g[1] = { cn, Wkt, bk, (void*)Kb,  0 };
  a3.g[2] = { cn, Wvt, bv, (void*)Vtb, 2 };
  gemm128<<<dim3(32, 8, 3), 256, 0, stream>>>(a3);

  flash_kernel<<<dim3(32, 16, 2), 256, 0, stream>>>(Qb, Kb, Vtb, Op0, Op1, L0, L1);

  combine_kernel<<<4096, 256, 0, stream>>>(Op0, Op1, L0, L1, AOb);

  gemm_o<<<dim3(32, 16), 256, 0, stream>>>(AOb, Wot, bo, (float*)d_out, query);
}

// Round 6
// 220.930 us; speedup vs baseline: 1.1173x; 1.1173x over previous
//
#include <hip/hip_runtime.h>
#include <hip/hip_bf16.h>

typedef unsigned short u16;
typedef unsigned long long u64;
typedef __bf16 bf16x8 __attribute__((ext_vector_type(8)));
typedef float f32x4 __attribute__((ext_vector_type(4)));

#define DIM 1024
#define NH 16
#define HD 64
// 0.125 * log2(e): folds the 1/sqrt(64) score scale and the exp->exp2 change of base
#define QSCALE 0.180336880972788f

__device__ __forceinline__ u16 f2bf(float f) {
  union { float f; unsigned u; } v; v.f = f;
  unsigned r = v.u + 0x7fffu + ((v.u >> 16) & 1u);
  return (u16)(r >> 16);
}

__device__ __forceinline__ unsigned pk2(float a, float b) {
  union { __hip_bfloat162 h; unsigned u; } cv;
  cv.h = __float22bfloat162_rn(make_float2(a, b));
  return cv.u;
}

__device__ __forceinline__ float bf2f(unsigned s) {
  union { unsigned u; float f; } v; v.u = s << 16; return v.f;
}

__device__ __forceinline__ float fexp2(float x) {
#if __has_builtin(__builtin_amdgcn_exp2f)
  return __builtin_amdgcn_exp2f(x);   // raw v_exp_f32, no OCML denormal fixup
#else
  return exp2f(x);
#endif
}

__device__ __forceinline__ void gld16(const u16* gp, u16* lp) {
  __builtin_amdgcn_global_load_lds(
      (const __attribute__((address_space(1))) unsigned int*)(const void*)gp,
      (__attribute__((address_space(3))) unsigned int*)(void*)lp, 16, 0, 0);
}

// ---------------- Fused prep: 2x LayerNorm + 4x weight transpose ----------------
__global__ __launch_bounds__(256) void prep_kernel(
    const float* __restrict__ q, const float* __restrict__ c,
    const float* __restrict__ gq, const float* __restrict__ bq,
    const float* __restrict__ gkv, const float* __restrict__ bkv,
    u16* __restrict__ qn, u16* __restrict__ cn,
    const float* W0, const float* W1, const float* W2, const float* W3,
    u16* O0, u16* O1, u16* O2, u16* O3) {
  __shared__ float red[2][4];
  __shared__ float t[32][33];
  int bid = blockIdx.x, tid = threadIdx.x;
  if (bid < 8192) {
    const float* x  = bid < 4096 ? q : c;
    const float* g  = bid < 4096 ? gq : gkv;
    const float* be = bid < 4096 ? bq : bkv;
    u16* out = bid < 4096 ? qn : cn;
    int row = bid & 4095;
    float4 v = ((const float4*)(x + (size_t)row * DIM))[tid];
    float s1 = v.x + v.y + v.z + v.w;
    float s2 = v.x * v.x + v.y * v.y + v.z * v.z + v.w * v.w;
#pragma unroll
    for (int o = 32; o >= 1; o >>= 1) { s1 += __shfl_xor(s1, o, 64); s2 += __shfl_xor(s2, o, 64); }
    int wv = tid >> 6;
    if ((tid & 63) == 0) { red[0][wv] = s1; red[1][wv] = s2; }
    __syncthreads();
    s1 = red[0][0] + red[0][1] + red[0][2] + red[0][3];
    s2 = red[1][0] + red[1][1] + red[1][2] + red[1][3];
    float mu = s1 * (1.f / DIM);
    float var = s2 * (1.f / DIM) - mu * mu;
    float rs = rsqrtf(var + 1e-5f);
    float4 gv = ((const float4*)g)[tid];
    float4 bv = ((const float4*)be)[tid];
    uint2 o2;
    o2.x = pk2((v.x - mu) * rs * gv.x + bv.x, (v.y - mu) * rs * gv.y + bv.y);
    o2.y = pk2((v.z - mu) * rs * gv.z + bv.z, (v.w - mu) * rs * gv.w + bv.w);
    ((uint2*)(out + (size_t)row * DIM))[tid] = o2;
  } else {
    int wid = bid - 8192;
    int z = wid >> 10;
    const float* W = z == 0 ? W0 : z == 1 ? W1 : z == 2 ? W2 : W3;
    u16* O        = z == 0 ? O0 : z == 1 ? O1 : z == 2 ? O2 : O3;
    int xy = wid & 1023;
    int bx = (xy & 31) * 32, by = (xy >> 5) * 32;
    int tx = tid & 31, ty = tid >> 5;
#pragma unroll
    for (int i = 0; i < 4; ++i) t[ty + i * 8][tx] = W[(size_t)(by + ty + i * 8) * DIM + bx + tx];
    __syncthreads();
#pragma unroll
    for (int i = 0; i < 4; ++i) O[(size_t)(bx + ty + i * 8) * DIM + by + tx] = f2bf(t[tx][ty + i * 8]);
  }
}

// ---------------- QKV projections: z=0 fused K+V (shared A tile), z=1 Q ----------------
// A[M,K] bf16, weights transposed Wt[n][k] bf16. 128x64 output tile, 4 waves 2x2.
// K out: bf16 row-major [B*2048,1024]. V out: Vt[(b*1024+n)][token] via swapped MFMA.
// Q out: bf16 row-major * QSCALE.
__global__ __launch_bounds__(256) void gemm_qkv(
    const u16* __restrict__ qn, const u16* __restrict__ cn,
    const u16* __restrict__ Wqt, const u16* __restrict__ Wkt, const u16* __restrict__ Wvt,
    const float* __restrict__ bq, const float* __restrict__ bk, const float* __restrict__ bv,
    u16* __restrict__ Qb, u16* __restrict__ Kb, u16* __restrict__ Vtb) {
  __shared__ __align__(16) u16 sm[(128 + 64 + 64) * 64];  // A | B0 | B1 = 32 KB
  u16* As  = sm;
  u16* B0s = sm + 128 * 64;
  u16* B1s = sm + 192 * 64;
  int tid = threadIdx.x, wave = tid >> 6, lane = tid & 63;
  int lr = lane & 15, quad = lane >> 4;
  int m0 = blockIdx.x * 128, n0 = blockIdx.y * 64;
  int wm = (wave >> 1) * 64, wn = (wave & 1) * 32;

  if (blockIdx.z == 0) {
    // ---- K + V fused over A = cn ----
    f32x4 acck[4][2] = {}, accv[4][2] = {};
    for (int kt = 0; kt < DIM; kt += 64) {
#pragma unroll
      for (int r = 0; r < 4; ++r) {
        int slot = tid + r * 256;
        int row = slot >> 3;
        int c = (slot & 7) ^ (row & 7);
        gld16(cn + (size_t)(m0 + row) * DIM + kt + c * 8, &As[slot * 8]);
      }
      {
        int slot = tid;
        int row = slot >> 3;
        int c = (slot & 7) ^ (row & 7);
        gld16(Wkt + (size_t)(n0 + row) * DIM + kt + c * 8, &B0s[slot * 8]);
        gld16(Wvt + (size_t)(n0 + row) * DIM + kt + c * 8, &B1s[slot * 8]);
        slot = tid + 256; row = slot >> 3; c = (slot & 7) ^ (row & 7);
        gld16(Wkt + (size_t)(n0 + row) * DIM + kt + c * 8, &B0s[slot * 8]);
        gld16(Wvt + (size_t)(n0 + row) * DIM + kt + c * 8, &B1s[slot * 8]);
      }
      __syncthreads();
#pragma unroll
      for (int kc = 0; kc < 2; ++kc) {
        int pc = ((kc * 4 + quad) ^ (lr & 7)) * 8;
        bf16x8 af[4], b0f[2], b1f[2];
#pragma unroll
        for (int i = 0; i < 4; ++i) af[i] = *(const bf16x8*)&As[(wm + i * 16 + lr) * 64 + pc];
#pragma unroll
        for (int j = 0; j < 2; ++j) {
          b0f[j] = *(const bf16x8*)&B0s[(wn + j * 16 + lr) * 64 + pc];
          b1f[j] = *(const bf16x8*)&B1s[(wn + j * 16 + lr) * 64 + pc];
        }
#pragma unroll
        for (int mi = 0; mi < 4; ++mi)
#pragma unroll
          for (int ni = 0; ni < 2; ++ni) {
            acck[mi][ni] = __builtin_amdgcn_mfma_f32_16x16x32_bf16(af[mi], b0f[ni], acck[mi][ni], 0, 0, 0);
            accv[mi][ni] = __builtin_amdgcn_mfma_f32_16x16x32_bf16(b1f[ni], af[mi], accv[mi][ni], 0, 0, 0);
          }
      }
      __syncthreads();
    }
    // K epilogue: row-major
#pragma unroll
    for (int mi = 0; mi < 4; ++mi)
#pragma unroll
      for (int ni = 0; ni < 2; ++ni) {
        int col = n0 + wn + ni * 16 + lr;
        float bb_ = bk[col];
        int row0 = m0 + wm + mi * 16 + quad * 4;
#pragma unroll
        for (int r = 0; r < 4; ++r)
          Kb[(size_t)(row0 + r) * DIM + col] = f2bf(acck[mi][ni][r] + bb_);
      }
    // V epilogue: accv = C^T (col=token m via lr, row=channel n via quad*4+r)
#pragma unroll
    for (int mi = 0; mi < 4; ++mi) {
      int m = m0 + wm + mi * 16 + lr;
      int bb = m >> 11, tt = m & 2047;
      u16* outb = Vtb + (((size_t)bb << 10)) * 2048 + tt;
#pragma unroll
      for (int ni = 0; ni < 2; ++ni) {
        int nbase = n0 + wn + ni * 16 + quad * 4;
#pragma unroll
        for (int r = 0; r < 4; ++r)
          outb[(size_t)(nbase + r) * 2048] = f2bf(accv[mi][ni][r] + bv[nbase + r]);
      }
    }
  } else {
    // ---- Q over A = qn ----
    f32x4 acc[4][2] = {};
    for (int kt = 0; kt < DIM; kt += 64) {
#pragma unroll
      for (int r = 0; r < 4; ++r) {
        int slot = tid + r * 256;
        int row = slot >> 3;
        int c = (slot & 7) ^ (row & 7);
        gld16(qn + (size_t)(m0 + row) * DIM + kt + c * 8, &As[slot * 8]);
      }
#pragma unroll
      for (int r = 0; r < 2; ++r) {
        int slot = tid + r * 256;
        int row = slot >> 3;
        int c = (slot & 7) ^ (row & 7);
        gld16(Wqt + (size_t)(n0 + row) * DIM + kt + c * 8, &B0s[slot * 8]);
      }
      __syncthreads();
#pragma unroll
      for (int kc = 0; kc < 2; ++kc) {
        int pc = ((kc * 4 + quad) ^ (lr & 7)) * 8;
        bf16x8 af[4], b0f[2];
#pragma unroll
        for (int i = 0; i < 4; ++i) af[i] = *(const bf16x8*)&As[(wm + i * 16 + lr) * 64 + pc];
#pragma unroll
        for (int j = 0; j < 2; ++j) b0f[j] = *(const bf16x8*)&B0s[(wn + j * 16 + lr) * 64 + pc];
#pragma unroll
        for (int mi = 0; mi < 4; ++mi)
#pragma unroll
          for (int ni = 0; ni < 2; ++ni)
            acc[mi][ni] = __builtin_amdgcn_mfma_f32_16x16x32_bf16(af[mi], b0f[ni], acc[mi][ni], 0, 0, 0);
      }
      __syncthreads();
    }
#pragma unroll
    for (int mi = 0; mi < 4; ++mi)
#pragma unroll
      for (int ni = 0; ni < 2; ++ni) {
        int col = n0 + wn + ni * 16 + lr;
        float bb_ = bq[col];
        int row0 = m0 + wm + mi * 16 + quad * 4;
#pragma unroll
        for (int r = 0; r < 4; ++r)
          Qb[(size_t)(row0 + r) * DIM + col] = f2bf((acc[mi][ni][r] + bb_) * QSCALE);
      }
  }
}

// ---------------- 128x64 GEMM, fp32 out + bias + residual (O proj) ----------------
__global__ __launch_bounds__(256) void gemm_o(const u16* __restrict__ A,
    const u16* __restrict__ Bt, const float* __restrict__ bias,
    float* __restrict__ out, const float* __restrict__ resid) {
  __shared__ __align__(16) u16 sm[(128 + 64) * 64];
  u16* As = sm;
  u16* Bs = sm + 128 * 64;
  int tid = threadIdx.x, wave = tid >> 6, lane = tid & 63;
  int lr = lane & 15, quad = lane >> 4;
  int m0 = blockIdx.x * 128, n0 = blockIdx.y * 64;
  int wm = (wave >> 1) * 64, wn = (wave & 1) * 32;
  f32x4 acc[4][2] = {};
  for (int kt = 0; kt < DIM; kt += 64) {
#pragma unroll
    for (int r = 0; r < 4; ++r) {
      int slot = tid + r * 256;
      int row = slot >> 3;
      int c = (slot & 7) ^ (row & 7);
      gld16(A + (size_t)(m0 + row) * DIM + kt + c * 8, &As[slot * 8]);
    }
#pragma unroll
    for (int r = 0; r < 2; ++r) {
      int slot = tid + r * 256;
      int row = slot >> 3;
      int c = (slot & 7) ^ (row & 7);
      gld16(Bt + (size_t)(n0 + row) * DIM + kt + c * 8, &Bs[slot * 8]);
    }
    __syncthreads();
#pragma unroll
    for (int kc = 0; kc < 2; ++kc) {
      int pc = ((kc * 4 + quad) ^ (lr & 7)) * 8;
      bf16x8 af[4], bfr[2];
#pragma unroll
      for (int i = 0; i < 4; ++i) af[i] = *(const bf16x8*)&As[(wm + i * 16 + lr) * 64 + pc];
#pragma unroll
      for (int j = 0; j < 2; ++j) bfr[j] = *(const bf16x8*)&Bs[(wn + j * 16 + lr) * 64 + pc];
#pragma unroll
      for (int mi = 0; mi < 4; ++mi)
#pragma unroll
        for (int ni = 0; ni < 2; ++ni)
          acc[mi][ni] = __builtin_amdgcn_mfma_f32_16x16x32_bf16(af[mi], bfr[ni], acc[mi][ni], 0, 0, 0);
    }
    __syncthreads();
  }
#pragma unroll
  for (int mi = 0; mi < 4; ++mi)
#pragma unroll
    for (int ni = 0; ni < 2; ++ni) {
      int col = n0 + wn + ni * 16 + lr;
      float bv = bias[col];
      int row0 = m0 + wm + mi * 16 + quad * 4;
#pragma unroll
      for (int r = 0; r < 4; ++r) {
        int row = row0 + r;
        out[(size_t)row * DIM + col] = acc[mi][ni][r] + bv + resid[(size_t)row * DIM + col];
      }
    }
}

// ---------------- Flash attention, split-K x2, 48KB LDS, 128B-row P ----------
// Q,K: [B*2048,1024] bf16 (Q pre-scaled). Vt: [(b*1024+h*64+d)][token] bf16.
// LDS u16: K0 @0, K1 @4096, V0 @8192, V1 @12288, P @16384 + wave*2048 (32q x 64k).
__global__ __launch_bounds__(256) void flash_kernel(const u16* __restrict__ Q,
    const u16* __restrict__ Kg, const u16* __restrict__ Vt,
    u16* __restrict__ O0, u16* __restrict__ O1,
    float* __restrict__ L0, float* __restrict__ L1) {
  __shared__ __align__(16) u16 lds[24576];  // 48 KB
  int tid = threadIdx.x, wave = tid >> 6, lane = tid & 63;
  int lr = lane & 15, quad = lane >> 4;
  int bh = blockIdx.x, b = bh >> 4, h = bh & 15;
  int q0 = blockIdx.y * 128;
  int split = blockIdx.z;
  u16* Op = split ? O1 : O0;
  float* Lp = split ? L1 : L0;
  int t0 = split * 1024;

  const u16* kbase = Kg + (size_t)(b * 2048 + t0) * DIM + h * HD;
  const u16* vbase = Vt + (size_t)(b * 1024 + h * HD) * 2048 + t0;

  // Q fragments straight from global (one-time)
  bf16x8 qf[2][2];
#pragma unroll
  for (int s = 0; s < 2; ++s)
#pragma unroll
    for (int kc = 0; kc < 2; ++kc)
      qf[s][kc] = *(const bf16x8*)&Q[((size_t)(b * 2048 + q0 + wave * 32 + s * 16 + lr)) * DIM +
                                     h * HD + kc * 32 + quad * 8];

  // strength-reduced staging pointers
  int slot0 = tid, slot1 = tid + 256;
  int r0 = slot0 >> 3, c0 = (slot0 & 7) ^ (r0 & 7);
  int r1 = slot1 >> 3, c1 = (slot1 & 7) ^ (r1 & 7);
  const u16* kp0 = kbase + (size_t)r0 * DIM + c0 * 8;
  const u16* kp1 = kbase + (size_t)r1 * DIM + c1 * 8;
  const u16* vp0 = vbase + (size_t)r0 * 2048 + c0 * 8;
  const u16* vp1 = vbase + (size_t)r1 * 2048 + c1 * 8;

  gld16(kp0, &lds[slot0 * 8]);
  gld16(kp1, &lds[slot1 * 8]);
  gld16(vp0, &lds[8192 + slot0 * 8]);
  gld16(vp1, &lds[8192 + slot1 * 8]);
  __syncthreads();

  u16* Pw = &lds[16384 + wave * 2048];  // 32 rows x 64 u16 (128B rows)
  float plsum[2] = {0.f, 0.f};
  f32x4 oacc[2][4] = {};

  for (int j = 0; j < 16; ++j) {
    int par = j & 1;
    const u16* kcb = &lds[par * 4096];
    const u16* vcb = &lds[8192 + par * 4096];
    if (j < 15) {
      int np = par ^ 1;
      kp0 += 64 * DIM; kp1 += 64 * DIM; vp0 += 64; vp1 += 64;
      gld16(kp0, &lds[np * 4096 + slot0 * 8]);
      gld16(kp1, &lds[np * 4096 + slot1 * 8]);
      gld16(vp0, &lds[8192 + np * 4096 + slot0 * 8]);
      gld16(vp1, &lds[8192 + np * 4096 + slot1 * 8]);
    }

    // S^T = K . Q^T
    f32x4 sf[2][4] = {};
#pragma unroll
    for (int kc = 0; kc < 2; ++kc) {
      int pc = ((kc * 4 + quad) ^ (lr & 7)) * 8;
#pragma unroll
      for (int ns = 0; ns < 4; ++ns) {
        bf16x8 kf = *(const bf16x8*)&kcb[(ns * 16 + lr) * 64 + pc];
#pragma unroll
        for (int s = 0; s < 2; ++s)
          sf[s][ns] = __builtin_amdgcn_mfma_f32_16x16x32_bf16(kf, qf[s][kc], sf[s][ns], 0, 0, 0);
      }
    }

    // p = exp2(s); 4 consecutive k per lane -> one 8B LDS write into wave-private P
#pragma unroll
    for (int s = 0; s < 2; ++s)
#pragma unroll
      for (int ns = 0; ns < 4; ++ns) {
        float p0 = fexp2(sf[s][ns][0]), p1 = fexp2(sf[s][ns][1]);
        float p2 = fexp2(sf[s][ns][2]), p3 = fexp2(sf[s][ns][3]);
        plsum[s] += (p0 + p1) + (p2 + p3);
        uint2 pk;
        pk.x = pk2(p0, p1);
        pk.y = pk2(p2, p3);
        int chunk = ns * 2 + (quad >> 1);
        int off = (s * 16 + lr) * 64 + ((chunk ^ (lr & 7)) * 8) + (quad & 1) * 4;
        *(uint2*)&Pw[off] = pk;
      }
    __threadfence_block();  // order wave-private P write -> read

    // O^T += V^T . P^T
#pragma unroll
    for (int kc = 0; kc < 2; ++kc) {
      int pc = ((kc * 4 + quad) ^ (lr & 7)) * 8;
      bf16x8 pf[2];
#pragma unroll
      for (int s = 0; s < 2; ++s)
        pf[s] = *(const bf16x8*)&Pw[(s * 16 + lr) * 64 + pc];
#pragma unroll
      for (int ds = 0; ds < 4; ++ds) {
        bf16x8 vf = *(const bf16x8*)&vcb[(ds * 16 + lr) * 64 + pc];
#pragma unroll
        for (int s = 0; s < 2; ++s)
          oacc[s][ds] = __builtin_amdgcn_mfma_f32_16x16x32_bf16(vf, pf[s], oacc[s][ds], 0, 0, 0);
      }
    }
    __syncthreads();
  }

#pragma unroll
  for (int s = 0; s < 2; ++s) {
    float l = plsum[s];
    l += __shfl_xor(l, 16, 64);
    l += __shfl_xor(l, 32, 64);
    size_t qrow = (size_t)(b * 2048 + q0 + wave * 32 + s * 16 + lr);
    if (quad == 0) Lp[qrow * 16 + h] = l;
#pragma unroll
    for (int ds = 0; ds < 4; ++ds) {
      uint2 pk;
      pk.x = pk2(oacc[s][ds][0], oacc[s][ds][1]);
      pk.y = pk2(oacc[s][ds][2], oacc[s][ds][3]);
      *(uint2*)&Op[qrow * DIM + h * HD + ds * 16 + quad * 4] = pk;
    }
  }
}

// ---------------- Combine split-K partials -> normalized bf16 AO ----------------
__global__ __launch_bounds__(256) void combine_kernel(const u16* __restrict__ O0,
    const u16* __restrict__ O1, const float* __restrict__ L0, const float* __restrict__ L1,
    u16* __restrict__ AO) {
  int row = blockIdx.x, tid = threadIdx.x;
  int h = tid >> 4;
  float rl = 1.f / (L0[row * 16 + h] + L1[row * 16 + h]);
  uint2 a = ((const uint2*)(O0 + (size_t)row * DIM))[tid];
  uint2 b = ((const uint2*)(O1 + (size_t)row * DIM))[tid];
  float v0 = (bf2f(a.x & 0xffff) + bf2f(b.x & 0xffff)) * rl;
  float v1 = (bf2f(a.x >> 16)    + bf2f(b.x >> 16))    * rl;
  float v2 = (bf2f(a.y & 0xffff) + bf2f(b.y & 0xffff)) * rl;
  float v3 = (bf2f(a.y >> 16)    + bf2f(b.y >> 16))    * rl;
  uint2 o;
  o.x = pk2(v0, v1);
  o.y = pk2(v2, v3);
  ((uint2*)(AO + (size_t)row * DIM))[tid] = o;
}

extern "C" void kernel_launch(void* const* d_in, const int* in_sizes, int n_in,
                              void* d_out, int out_size, void* d_ws, size_t ws_size,
                              hipStream_t stream) {
  const float* query   = (const float*)d_in[0];
  const float* context = (const float*)d_in[1];
  const float* Wq = (const float*)d_in[2];
  const float* bq = (const float*)d_in[3];
  const float* Wk = (const float*)d_in[4];
  const float* bk = (const float*)d_in[5];
  const float* Wv = (const float*)d_in[6];
  const float* bv = (const float*)d_in[7];
  const float* Wo = (const float*)d_in[8];
  const float* bo = (const float*)d_in[9];
  const float* gq    = (const float*)d_in[10];
  const float* betaq = (const float*)d_in[11];
  const float* gkv   = (const float*)d_in[12];
  const float* betakv= (const float*)d_in[13];
  (void)in_sizes; (void)n_in; (void)out_size; (void)ws_size;

  char* ws = (char*)d_ws;
  const size_t MB = (size_t)1 << 20;
  u16* qn  = (u16*)(ws + 0 * MB);   // dead after QKV gemm; reused by Op0
  u16* cn  = (u16*)(ws + 8 * MB);   // dead after QKV gemm; reused by Op1
  u16* Wqt = (u16*)(ws + 16 * MB);  // dead after QKV; L0/L1 alias here
  u16* Wkt = (u16*)(ws + 18 * MB);
  u16* Wvt = (u16*)(ws + 20 * MB);
  u16* Wot = (u16*)(ws + 22 * MB);  // alive until O proj
  u16* Qb  = (u16*)(ws + 24 * MB);
  u16* Kb  = (u16*)(ws + 32 * MB);
  u16* Vtb = (u16*)(ws + 40 * MB);
  u16* AOb = (u16*)(ws + 48 * MB);
  u16* Op0 = qn;
  u16* Op1 = cn;
  float* L0 = (float*)(ws + 16 * MB);
  float* L1 = (float*)(ws + 16 * MB + 256 * 1024);

  prep_kernel<<<12288, 256, 0, stream>>>(query, context, gq, betaq, gkv, betakv,
                                         qn, cn, Wq, Wk, Wv, Wo, Wqt, Wkt, Wvt, Wot);

  gemm_qkv<<<dim3(32, 16, 2), 256, 0, stream>>>(qn, cn, Wqt, Wkt, Wvt,
                                                bq, bk, bv, Qb, Kb, Vtb);

  flash_kernel<<<dim3(32, 16, 2), 256, 0, stream>>>(Qb, Kb, Vtb, Op0, Op1, L0, L1);

  combine_kernel<<<4096, 256, 0, stream>>>(Op0, Op1, L0, L1, AOb);

  gemm_o<<<dim3(32, 16), 256, 0, stream>>>(AOb, Wot, bo, (float*)d_out, query);
}